// Round 10
// baseline (480.975 us; speedup 1.0000x reference)
//
#include <hip/hip_runtime.h>
#include <hip/hip_bf16.h>
#include <math.h>

// ---------------------------------------------------------------------------
// WaveFormer on MI355X.  B=16, C=384, H=W=64, T=B*H*W=65536 tokens.
//   [conv3x3 dw ∥ prep] -> pl2tok -> [GEMM1(lin) ∥ f2bf(freq)] -> xs PLANE,
//   z token, freq bf16 -> GEMM2(pure) -> v PLANE
//   spectral per (b,c) plane: Wn^T((Wn P Wn^T) .* mod(v)) Wn, mod inline (r7)
//   fused LN(xo plane) * silu(z) -> y token -> GEMM3(out) -> d_out fp32
// GEMMs: m97-style 128x128 tile, BK=32, double-buffered global_load_lds w=16,
// XOR-swizzled LDS, XCD-aware 1D grid, __launch_bounds__(256,3) (r9: VGPR
// 120->60, occupancy 19.5->34.5%, split 71->63us).
// r10: grid-partitioned kernel unions for the two data-independent pairs:
//   (a) f2bf8(freq) merged into gemm_split's launch (blocks 3072..15359) --
//       streaming-BW blocks fill split's latency stalls (~90us seq -> ~70);
//   (b) prep merged into conv (blocks 6144..6735).
// r8: spectral tiles XOR-swizzled (25.6M conflict cycles -> ~0).
// lnfuse v2: 32 tok/block, linearized output (r6).
// Workspace: 2 x 48MB ping-pong + ~1.2MB weights. d_out doubles as xs/z
// scratch until GEMM3.
// ---------------------------------------------------------------------------

typedef __attribute__((ext_vector_type(8))) short short8;   // 8 bf16
typedef __attribute__((ext_vector_type(4))) float floatx4;

#define PIF 3.14159265358979323846f

__device__ __forceinline__ short f2bf(float f) {
    union { float f; unsigned u; } v; v.f = f;
    unsigned r = v.u + 0x7fffu + ((v.u >> 16) & 1u);   // RNE
    return (short)(r >> 16);
}
__device__ __forceinline__ float bf2f(short s) {
    union { unsigned u; float f; } v;
    v.u = ((unsigned)(unsigned short)s) << 16;
    return v.f;
}
// erf(x) via Abramowitz-Stegun 7.1.26 (max abs err 1.5e-7), fast __expf
__device__ __forceinline__ float fast_erf(float x) {
    float ax = fabsf(x);
    float t = 1.0f / fmaf(0.3275911f, ax, 1.0f);
    float poly = t * fmaf(t, fmaf(t, fmaf(t, fmaf(t, 1.061405429f, -1.453152027f),
                                          1.421413741f), -0.284496736f), 0.254829592f);
    float er = 1.0f - poly * __expf(-ax * ax);
    return copysignf(er, x);
}

// async global->LDS, 16B per lane. lds ptr must be wave-uniform base.
__device__ __forceinline__ void gload16(const short* g, short* l) {
    __builtin_amdgcn_global_load_lds(
        (const __attribute__((address_space(1))) void*)g,
        (__attribute__((address_space(3))) void*)l, 16, 0, 0);
}

// [64][64] bf16 tile swizzle: flip 16B slot by row bits (2-way banks = free)
__device__ __forceinline__ int swi(int r, int c) {
    return (r << 6) + (c ^ ((((r) & 7) ^ ((r >> 3) & 7)) << 3));
}

// ---- conv3x3 dw (blocks 0..6143) ∥ prep: weight converts + DCT (6144..) ----
__global__ __launch_bounds__(256) void k_conv(const float* __restrict__ x,
                                              const float* __restrict__ w,
                                              const float* __restrict__ bias,
                                              short* __restrict__ out,
                                              const float* __restrict__ lin_w,
                                              const float* __restrict__ tok_w,
                                              const float* __restrict__ out_w,
                                              short* __restrict__ linw_bf,
                                              short* __restrict__ tokw_bf,
                                              short* __restrict__ outw_bf,
                                              short* __restrict__ wn,
                                              short* __restrict__ wnt) {
    __shared__ float sp[4096];
    int bid = blockIdx.x;
    if (bid >= 6144) {
        int b = bid - 6144;
        if (b < 576) {
            const float* src; short* dst; int base;
            if (b < 288)      { src = lin_w; dst = linw_bf; base = b; }
            else if (b < 432) { src = tok_w; dst = tokw_bf; base = b - 288; }
            else              { src = out_w; dst = outw_bf; base = b - 432; }
            int i = (base * 256 + threadIdx.x) * 4;
            float4 f = *(const float4*)(src + i);
            short4 o;
            o.x = f2bf(f.x); o.y = f2bf(f.y); o.z = f2bf(f.z); o.w = f2bf(f.w);
            *(short4*)(dst + i) = o;
        } else {
            int i = (b - 576) * 256 + threadIdx.x;   // 0..4095
            int n = i >> 6, h = i & 63;
            float v = cosf((float)n * ((float)h + 0.5f) * (PIF / 64.0f)) * sqrtf(2.0f / 64.0f);
            if (n == 0) v *= 0.70710678118654752f;
            short bb = f2bf(v);
            wn[n * 64 + h]  = bb;   // [n][h]
            wnt[h * 64 + n] = bb;   // [h][n]
        }
        return;
    }
    int bc = bid;                     // b*384 + c
    int c = bc % 384;
    int tid = threadIdx.x;
    const float* xp = x + (size_t)bc * 4096;
    for (int i = 0; i < 4; i++) {
        int e = i * 1024 + tid * 4;
        *(float4*)(sp + e) = *(const float4*)(xp + e);
    }
    float wt[9];
    #pragma unroll
    for (int j = 0; j < 9; j++) wt[j] = w[c * 9 + j];
    float bv = bias[c];
    __syncthreads();
    short* op = out + (size_t)bc * 4096;
    for (int i = 0; i < 16; i++) {
        int hw = i * 256 + tid;
        int h = hw >> 6, ww = hw & 63;
        float acc = bv;
        #pragma unroll
        for (int dh = 0; dh < 3; dh++) {
            int ih = h + dh - 1;
            if (ih < 0 || ih > 63) continue;
            #pragma unroll
            for (int dw = 0; dw < 3; dw++) {
                int iw = ww + dw - 1;
                if (iw < 0 || iw > 63) continue;
                acc += sp[ih * 64 + iw] * wt[dh * 3 + dw];
            }
        }
        op[hw] = f2bf(acc);
    }
}

// ------- plane [B][C][4096] -> token [T][384] (xd only), short8 both sides --
__global__ __launch_bounds__(256) void k_pl2tok(const short* __restrict__ src,
                                                short* __restrict__ dst) {
    __shared__ short tile[4096];       // [hw][c], swi-swizzled
    int ct = blockIdx.x, ht = blockIdx.y, b = blockIdx.z;
    int tid = threadIdx.x;
    const short* sp = src + ((size_t)b * 384 + ct * 64) * 4096 + ht * 64;
    #pragma unroll
    for (int i = 0; i < 2; i++) {
        int q = i * 256 + tid;
        int r = q >> 3, c8 = (q & 7) * 8;          // r=c-local, c8=hw-col chunk
        short8 v = *(const short8*)(sp + (size_t)r * 4096 + c8);
        #pragma unroll
        for (int j = 0; j < 8; j++) tile[swi(c8 + j, r)] = v[j];   // tile[hw][c]
    }
    __syncthreads();
    short* dp = dst + ((size_t)b * 4096 + ht * 64) * 384 + ct * 64;
    #pragma unroll
    for (int i = 0; i < 2; i++) {
        int q = i * 256 + tid;
        int r2 = q >> 3, c8 = (q & 7) * 8;         // r2=hw row, c8=c-col chunk
        short8 v = *(const short8*)(tile + swi(r2, c8));
        *(short8*)(dp + (size_t)r2 * 384 + c8) = v;
    }
}

// ---------------------------------------------------------------------------
// Shared GEMM core (bf16 A): D-tile 128x128, K=384, BK=32, 256 threads.
// XOR-swizzled tile: 16B slot q holds chunk (row=q>>2, koff=(q&3)^((q>>3)&3)).
// smem: ldsA [2][512 slots] at 0, ldsB same at +8192 shorts.
// ---------------------------------------------------------------------------
__device__ __forceinline__ void mm_core(const short* __restrict__ A,
                                        const short* __restrict__ Bw,
                                        int row_base, int col_base,
                                        short* smem, floatx4 (&acc)[4][4]) {
    const int K = 384;
    int tid = threadIdx.x;
    int wid = tid >> 6, lane = tid & 63;
    int quad = lane >> 4, l16 = lane & 15;
    int rowh = (wid >> 1) * 64, colh = (wid & 1) * 64;
    short* ldsA = smem;
    short* ldsB = smem + 8192;
    const short* ga = A + (size_t)row_base * K;
    const short* gb = Bw + (size_t)col_base * K;

    int q0 = tid, q1 = 256 + tid;
    int r0 = q0 >> 2, o0 = ((q0 & 3) ^ ((q0 >> 3) & 3)) * 8;
    int r1 = q1 >> 2, o1 = ((q1 & 3) ^ ((q1 >> 3) & 3)) * 8;
    short* la0 = ldsA + (wid * 64) * 8;          // wave-uniform dests
    short* la1 = ldsA + (256 + wid * 64) * 8;
    short* lb0 = ldsB + (wid * 64) * 8;
    short* lb1 = ldsB + (256 + wid * 64) * 8;

    auto stage = [&](int ks, int buf) {
        int k0 = ks * 32;
        gload16(ga + (size_t)r0 * K + k0 + o0, la0 + buf * 4096);
        gload16(ga + (size_t)r1 * K + k0 + o1, la1 + buf * 4096);
        gload16(gb + (size_t)r0 * K + k0 + o0, lb0 + buf * 4096);
        gload16(gb + (size_t)r1 * K + k0 + o1, lb1 + buf * 4096);
    };

    int ksw = (quad ^ ((l16 >> 1) & 3)) * 8;     // per-lane swizzled k-slot

    stage(0, 0);
    __syncthreads();
    #pragma unroll 2
    for (int ks = 0; ks < 12; ++ks) {
        int cur = ks & 1;
        if (ks < 11) stage(ks + 1, cur ^ 1);
        short8 af[4], bfr[4];
        #pragma unroll
        for (int s = 0; s < 4; s++) {
            af[s]  = *(const short8*)(ldsA + cur * 4096 + (rowh + s * 16 + l16) * 32 + ksw);
            bfr[s] = *(const short8*)(ldsB + cur * 4096 + (colh + s * 16 + l16) * 32 + ksw);
        }
        #pragma unroll
        for (int i = 0; i < 4; i++)
            #pragma unroll
            for (int j = 0; j < 4; j++)
                acc[i][j] = __builtin_amdgcn_mfma_f32_16x16x32_bf16(af[i], bfr[j], acc[i][j], 0, 0, 0);
        __syncthreads();
    }
}

// -------- GEMM1 (blocks 0..3071): D[M,768]=A*lin_w^T+b; xs PLANE, z token --
// -------- ∥ f2bf8(freq) (blocks 3072..15359): fp32->bf16, 8/thread --------
__global__ __launch_bounds__(256, 3) void k_gemm_split(const short* __restrict__ A,
                                                       const short* __restrict__ Bw,
                                                       const float* __restrict__ bias,
                                                       short* __restrict__ xs_pl,
                                                       short* __restrict__ z_tok,
                                                       const float* __restrict__ freqf,
                                                       short* __restrict__ freqbf) {
    __shared__ __align__(16) short smem[17408];  // staging 16384 | tile 128*136
    int bid = blockIdx.x;
    if (bid >= 3072) {
        int i = ((bid - 3072) * 256 + threadIdx.x) * 8;
        float4 a = *(const float4*)(freqf + i);
        float4 b = *(const float4*)(freqf + i + 4);
        short8 o;
        o[0] = f2bf(a.x); o[1] = f2bf(a.y); o[2] = f2bf(a.z); o[3] = f2bf(a.w);
        o[4] = f2bf(b.x); o[5] = f2bf(b.y); o[6] = f2bf(b.z); o[7] = f2bf(b.w);
        *(short8*)(freqbf + i) = o;
        return;
    }
    int xcd = bid & 7, local = bid >> 3;         // 384 blocks per XCD
    int bx = local % 6;
    int by = xcd * 64 + local / 6;
    int row_base = by * 128, col_base = bx * 128;
    int tid = threadIdx.x;
    int wid = tid >> 6, lane = tid & 63, quad = lane >> 4, l16 = lane & 15;
    int rowh = (wid >> 1) * 64, colh = (wid & 1) * 64;

    floatx4 zero = {0.f, 0.f, 0.f, 0.f};
    floatx4 acc[4][4];
    #pragma unroll
    for (int i = 0; i < 4; i++)
        #pragma unroll
        for (int j = 0; j < 4; j++) acc[i][j] = zero;

    mm_core(A, Bw, row_base, col_base, smem, acc);

    if (bx < 3) {
        // xs half: transpose through smem (staging dead), store plane layout
        #pragma unroll
        for (int i = 0; i < 4; i++)
            #pragma unroll
            for (int j = 0; j < 4; j++) {
                int cl = colh + j * 16 + l16;            // channel-local 0..127
                float bs = bias[col_base + cl];
                #pragma unroll
                for (int r = 0; r < 4; r++) {
                    int rl = rowh + i * 16 + quad * 4 + r;   // token-local 0..127
                    smem[cl * 136 + rl] = f2bf(acc[i][j][r] + bs);
                }
            }
        __syncthreads();
        int t0 = row_base;                 // 128 tokens, same b
        int b = t0 >> 12, hw0 = t0 & 4095;
        for (int it = 0; it < 8; it++) {
            int q = it * 256 + tid;
            int cl = q >> 4, t8 = (q & 15) * 8;
            short8 vv = *(const short8*)(smem + cl * 136 + t8);
            int c = col_base + cl;
            *(short8*)(xs_pl + ((size_t)b * 384 + c) * 4096 + hw0 + t8) = vv;
        }
    } else {
        // z half: token layout direct
        #pragma unroll
        for (int i = 0; i < 4; i++)
            #pragma unroll
            for (int j = 0; j < 4; j++) {
                int col = col_base + colh + j * 16 + l16;
                float bs = bias[col];
                int cc = col - 384;
                #pragma unroll
                for (int r = 0; r < 4; r++) {
                    int row = row_base + rowh + i * 16 + quad * 4 + r;
                    z_tok[(size_t)row * 384 + cc] = f2bf(acc[i][j][r] + bs);
                }
            }
    }
}

// -------- GEMM2 (pure): v = freq @ tokw^T + b, stored PLANE layout ---------
__global__ __launch_bounds__(256, 3) void k_gemm_mod(const short* __restrict__ A,
                                                     const short* __restrict__ Bw,
                                                     const float* __restrict__ bias,
                                                     short* __restrict__ Dpl) {
    __shared__ __align__(16) short smem[17408];
    int bid = blockIdx.x;
    int xcd = bid & 7, local = bid >> 3;         // 192 blocks per XCD
    int bx = local % 3;
    int by = xcd * 64 + local / 3;
    int row_base = by * 128, col_base = bx * 128;
    int tid = threadIdx.x;
    int wid = tid >> 6, lane = tid & 63, quad = lane >> 4, l16 = lane & 15;
    int rowh = (wid >> 1) * 64, colh = (wid & 1) * 64;

    floatx4 zero = {0.f, 0.f, 0.f, 0.f};
    floatx4 acc[4][4];
    #pragma unroll
    for (int i = 0; i < 4; i++)
        #pragma unroll
        for (int j = 0; j < 4; j++) acc[i][j] = zero;

    mm_core(A, Bw, row_base, col_base, smem, acc);

    // transpose through smem (staging dead), store v plane layout
    #pragma unroll
    for (int i = 0; i < 4; i++) {
        #pragma unroll
        for (int j = 0; j < 4; j++) {
            int cl = colh + j * 16 + l16;
            float bs = bias[col_base + cl];
            #pragma unroll
            for (int r = 0; r < 4; r++) {
                int rl = rowh + i * 16 + quad * 4 + r;
                smem[cl * 136 + rl] = f2bf(acc[i][j][r] + bs);
            }
        }
    }
    __syncthreads();
    int t0 = row_base;
    int b = t0 >> 12, hw0 = t0 & 4095;
    for (int it = 0; it < 8; it++) {
        int q = it * 256 + tid;
        int cl = q >> 4, t8 = (q & 15) * 8;
        short8 vv = *(const short8*)(smem + cl * 136 + t8);
        int c = col_base + cl;
        *(short8*)(Dpl + ((size_t)b * 384 + c) * 4096 + hw0 + t8) = vv;
    }
}

// ---------------- spectral: per (b,c) plane, 4 chained 64x64x64 MFMA GEMMs ----
// xo = Wn^T ((Wn P Wn^T) .* mod(v)) Wn, mod computed inline from v plane.
// All LDS tiles XOR-swizzled via swi(); Wn/Wt/M use pre-swizzled global slot.
__global__ __launch_bounds__(256) void k_spectral(const short* __restrict__ xs,   // [B][C][4096] [h][w]
                                                  const short* __restrict__ vpl,  // [B][C][4096] [n][m] pre-act
                                                  const short* __restrict__ wn,   // [n][h]
                                                  const short* __restrict__ wnt,  // [h][n]
                                                  const float* __restrict__ cp,
                                                  const float* __restrict__ ap,
                                                  short* __restrict__ xo) {       // [B][C][4096]
    __shared__ short sWn[4096], sWt[4096], sP[4096], sM[4096], sT[4096];
    int bc = blockIdx.x;
    int tid = threadIdx.x;
    int wid = tid >> 6, lane = tid & 63, quad = lane >> 4, l16 = lane & 15;
    const short* xp = xs + (size_t)bc * 4096;
    const short* mp = vpl + (size_t)bc * 4096;
    floatx4 zero = {0.f, 0.f, 0.f, 0.f};

    for (int i = 0; i < 2; i++) {
        int e = i * 2048 + tid * 8;
        int row = e >> 6, slot = (e >> 3) & 7;
        // pre-swizzled global slot; LDS store linear -> content[row][c^S(row)]
        int gx = (row << 6) + (((slot ^ (row & 7) ^ ((row >> 3) & 7)) & 7) << 3);
        *(short8*)(sWn + e) = *(const short8*)(wn + gx);
        *(short8*)(sWt + e) = *(const short8*)(wnt + gx);
        *(short8*)(sM + e)  = *(const short8*)(mp + gx);
        short8 pv = *(const short8*)(xp + e);       // linear coalesced read
        int h = row, w0 = e & 63;
        #pragma unroll
        for (int j = 0; j < 8; j++) sP[swi(w0 + j, h)] = pv[j];   // sP = P^T [w][h]
    }
    __syncthreads();

    int mrow = wid * 16;   // this wave's 16 output rows at every stage
    floatx4 acc[4];

    // S1: T1[n][w] = sum_h Wn[n][h] P[h][w]
    #pragma unroll
    for (int j = 0; j < 4; j++) acc[j] = zero;
    #pragma unroll
    for (int ks = 0; ks < 2; ks++) {
        int k0 = ks * 32 + quad * 8;
        short8 a = *(const short8*)(sWn + swi(mrow + l16, k0));
        #pragma unroll
        for (int j = 0; j < 4; j++) {
            short8 b = *(const short8*)(sP + swi(j * 16 + l16, k0));
            acc[j] = __builtin_amdgcn_mfma_f32_16x16x32_bf16(a, b, acc[j], 0, 0, 0);
        }
    }
    #pragma unroll
    for (int j = 0; j < 4; j++)
        #pragma unroll
        for (int r = 0; r < 4; r++)
            sT[swi(mrow + quad * 4 + r, j * 16 + l16)] = f2bf(acc[j][r]);  // sT = T1 [n][w]
    __syncthreads();

    // S2: T2[n][m] = sum_w T1[n][w] Wn[m][w]
    #pragma unroll
    for (int j = 0; j < 4; j++) acc[j] = zero;
    #pragma unroll
    for (int ks = 0; ks < 2; ks++) {
        int k0 = ks * 32 + quad * 8;
        short8 a = *(const short8*)(sT + swi(mrow + l16, k0));
        #pragma unroll
        for (int j = 0; j < 4; j++) {
            short8 b = *(const short8*)(sWn + swi(j * 16 + l16, k0));
            acc[j] = __builtin_amdgcn_mfma_f32_16x16x32_bf16(a, b, acc[j], 0, 0, 0);
        }
    }
    __syncthreads();
    // epilogue: compute mod from v inline, multiply, store transposed [m][n]
    {
        float cv = cp[0], av = ap[0];
        float inv_c = 1.0f / (cv + 1e-8f);
        float gfac = 1.0f + 0.5f * av;
        #pragma unroll
        for (int j = 0; j < 4; j++)
            #pragma unroll
            for (int r = 0; r < 4; r++) {
                int n = mrow + quad * 4 + r, m = j * 16 + l16;
                float v = bf2f(sM[swi(n, m)]);
                float t = 0.5f * v * (1.0f + fast_erf(v * 0.70710678118654752f));
                float sn, cs;
                __sincosf(cv * t, &sn, &cs);
                float fac = cs + sn * inv_c * gfac;
                float wnf = (float)n * (PIF / 64.0f);
                float wmf = (float)m * (PIF / 64.0f);
                float mod = fac * __expf(-(wnf * wnf + wmf * wmf) * t);
                sP[swi(m, n)] = f2bf(acc[j][r] * mod);
            }
    }
    __syncthreads();

    // S3: T3[h][m] = sum_n WnT[h][n] T2'[n][m]
    #pragma unroll
    for (int j = 0; j < 4; j++) acc[j] = zero;
    #pragma unroll
    for (int ks = 0; ks < 2; ks++) {
        int k0 = ks * 32 + quad * 8;
        short8 a = *(const short8*)(sWt + swi(mrow + l16, k0));
        #pragma unroll
        for (int j = 0; j < 4; j++) {
            short8 b = *(const short8*)(sP + swi(j * 16 + l16, k0));
            acc[j] = __builtin_amdgcn_mfma_f32_16x16x32_bf16(a, b, acc[j], 0, 0, 0);
        }
    }
    __syncthreads();
    #pragma unroll
    for (int j = 0; j < 4; j++)
        #pragma unroll
        for (int r = 0; r < 4; r++)
            sT[swi(mrow + quad * 4 + r, j * 16 + l16)] = f2bf(acc[j][r]);  // sT = T3 [h][m]
    __syncthreads();

    // S4: XO[h][w] = sum_m T3[h][m] Wn[m][w]
    #pragma unroll
    for (int j = 0; j < 4; j++) acc[j] = zero;
    #pragma unroll
    for (int ks = 0; ks < 2; ks++) {
        int k0 = ks * 32 + quad * 8;
        short8 a = *(const short8*)(sT + swi(mrow + l16, k0));
        #pragma unroll
        for (int j = 0; j < 4; j++) {
            short8 b = *(const short8*)(sWt + swi(j * 16 + l16, k0));
            acc[j] = __builtin_amdgcn_mfma_f32_16x16x32_bf16(a, b, acc[j], 0, 0, 0);
        }
    }
    short* op = xo + (size_t)bc * 4096;
    #pragma unroll
    for (int j = 0; j < 4; j++)
        #pragma unroll
        for (int r = 0; r < 4; r++) {
            int h = mrow + quad * 4 + r, w = j * 16 + l16;
            op[h * 64 + w] = f2bf(acc[j][r]);
        }
}

// ------- fused v2: xo PLANE -> LN over C -> * silu(z) -> y token ----------
// 32 tokens/block (one b, contiguous hw), grid 2048. LDS ~25 KB -> 6 blk/CU.
// Output loop linear in m: y/z offset = t0*384 + 8*m (fully coalesced).
__global__ __launch_bounds__(256) void k_lnfuse(const short* __restrict__ xo_pl, // [B][C][4096]
                                                const short* __restrict__ z,     // [T][384]
                                                const float* __restrict__ g,
                                                const float* __restrict__ bb,
                                                short* __restrict__ y) {         // [T][384]
    __shared__ short tile[32 * 392];     // [tok][c], stride 392 (16B-aligned rows)
    __shared__ float smu[32], srstd[32];
    int tid = threadIdx.x;
    int t0 = blockIdx.x * 32;
    int b = t0 >> 12, hw0 = t0 & 4095;

    // fill: 1536 chunks (384 c x 4 t8-chunks); tch fastest -> 64B global segs
    for (int it = 0; it < 6; it++) {
        int m = it * 256 + tid;
        int c = m >> 2, t8 = (m & 3) * 8;
        short8 v = *(const short8*)(xo_pl + ((size_t)b * 384 + c) * 4096 + hw0 + t8);
        #pragma unroll
        for (int j = 0; j < 8; j++) tile[(t8 + j) * 392 + c] = v[j];
    }
    __syncthreads();

    // LN stats: 8 threads per token (t = tid>>3), 48 channels each
    {
        int t = tid >> 3, g8 = tid & 7;
        const short* trow = tile + t * 392 + g8 * 48;
        float s = 0.f, sq = 0.f;
        #pragma unroll
        for (int i = 0; i < 6; i++) {
            short8 xv = *(const short8*)(trow + i * 8);
            #pragma unroll
            for (int j = 0; j < 8; j++) {
                float f = bf2f(xv[j]);
                s += f; sq += f * f;
            }
        }
        s  += __shfl_xor(s, 1, 64);  s  += __shfl_xor(s, 2, 64);  s  += __shfl_xor(s, 4, 64);
        sq += __shfl_xor(sq, 1, 64); sq += __shfl_xor(sq, 2, 64); sq += __shfl_xor(sq, 4, 64);
        if (g8 == 0) {
            float mu = s * (1.0f / 384.0f);
            float var = sq * (1.0f / 384.0f) - mu * mu;
            smu[t] = mu;
            srstd[t] = rsqrtf(var + 1e-5f);
        }
    }
    __syncthreads();

    // output: linear chunks, tok = m/48, ch = (m%48)*8; y/z addr = t0*384+8m
    for (int it = 0; it < 6; it++) {
        int m = it * 256 + tid;
        int tok = m / 48, ch = (m - tok * 48) * 8;
        float mu = smu[tok], rstd = srstd[tok];
        short8 xv = *(const short8*)(tile + tok * 392 + ch);
        const size_t goff = (size_t)(t0 + tok) * 384 + ch;
        short8 zv = *(const short8*)(z + goff);
        float4 g0 = *(const float4*)(g + ch);
        float4 g1 = *(const float4*)(g + ch + 4);
        float4 b0 = *(const float4*)(bb + ch);
        float4 b1 = *(const float4*)(bb + ch + 4);
        float gv[8] = {g0.x, g0.y, g0.z, g0.w, g1.x, g1.y, g1.z, g1.w};
        float bv[8] = {b0.x, b0.y, b0.z, b0.w, b1.x, b1.y, b1.z, b1.w};
        short8 ov;
        #pragma unroll
        for (int j = 0; j < 8; j++) {
            float zz = bf2f(zv[j]);
            float sil = zz / (1.f + __expf(-zz));
            float o = (bf2f(xv[j]) - mu) * rstd * gv[j] + bv[j];
            ov[j] = f2bf(o * sil);
        }
        *(short8*)(y + goff) = ov;
    }
}

// -------- GEMM3: out[M,384] = Y[M,384] * out_w^T + bias, fp32 store ---------
__global__ __launch_bounds__(256, 3) void k_gemm_f32out(const short* __restrict__ A,
                                                        const short* __restrict__ Bw,
                                                        const float* __restrict__ bias,
                                                        float* __restrict__ D) {
    __shared__ __align__(16) short smem[17408];
    const int N = 384;
    int bid = blockIdx.x;
    int xcd = bid & 7, local = bid >> 3;
    int bx = local % 3;
    int by = xcd * 64 + local / 3;
    int row_base = by * 128, col_base = bx * 128;
    int tid = threadIdx.x;
    int wid = tid >> 6, lane = tid & 63, quad = lane >> 4, l16 = lane & 15;
    int rowh = (wid >> 1) * 64, colh = (wid & 1) * 64;

    floatx4 zero = {0.f, 0.f, 0.f, 0.f};
    floatx4 acc[4][4];
    #pragma unroll
    for (int i = 0; i < 4; i++)
        #pragma unroll
        for (int j = 0; j < 4; j++) acc[i][j] = zero;

    mm_core(A, Bw, row_base, col_base, smem, acc);

    #pragma unroll
    for (int i = 0; i < 4; i++) {
        #pragma unroll
        for (int j = 0; j < 4; j++) {
            int col = col_base + colh + j * 16 + l16;
            float bs = bias[col];
            #pragma unroll
            for (int r = 0; r < 4; r++) {
                int row = row_base + rowh + i * 16 + quad * 4 + r;
                D[(size_t)row * N + col] = acc[i][j][r] + bs;
            }
        }
    }
}

// ---------------------------------------------------------------------------
extern "C" void kernel_launch(void* const* d_in, const int* in_sizes, int n_in,
                              void* d_out, int out_size, void* d_ws, size_t ws_size,
                              hipStream_t stream) {
    const float* x     = (const float*)d_in[0];
    const float* freq  = (const float*)d_in[1];
    const float* dw_w  = (const float*)d_in[2];
    const float* dw_b  = (const float*)d_in[3];
    const float* lin_w = (const float*)d_in[4];
    const float* lin_b = (const float*)d_in[5];
    const float* tok_w = (const float*)d_in[6];
    const float* tok_b = (const float*)d_in[7];
    const float* ln_g  = (const float*)d_in[8];
    const float* ln_b  = (const float*)d_in[9];
    const float* out_w = (const float*)d_in[10];
    const float* out_b = (const float*)d_in[11];
    const float* cp    = (const float*)d_in[12];
    const float* ap    = (const float*)d_in[13];
    float* out = (float*)d_out;
    (void)in_sizes; (void)n_in; (void)ws_size;

    // d_out (96MiB fp32) doubles as two 48MiB bf16 scratch tensors until GEMM3.
    const size_t TC = (size_t)65536 * 384;   // 25165824
    short* bufA = (short*)d_out;             // xs plane (dead after spectral)
    short* bufB = (short*)d_out + TC;        // z token (alive until lnfuse)

    char* ws = (char*)d_ws;
    size_t off = 0;
    auto alloc = [&](size_t bytes) {
        char* p = ws + off; off += (bytes + 255) & ~(size_t)255; return p;
    };
    short* wn_bf   = (short*)alloc(4096 * 2);
    short* wnt_bf  = (short*)alloc(4096 * 2);
    short* linw_bf = (short*)alloc((size_t)294912 * 2);
    short* tokw_bf = (short*)alloc((size_t)147456 * 2);
    short* outw_bf = (short*)alloc((size_t)147456 * 2);
    short* bufC    = (short*)alloc(TC * 2);  // xd token -> v plane -> y token
    short* bufE    = (short*)alloc(TC * 2);  // xd plane -> freq bf16 -> xo plane
    // total ws: ~98.3 MB

    // conv (0..6143) ∥ prep (6144..6735)
    k_conv<<<6736, 256, 0, stream>>>(x, dw_w, dw_b, bufE,
                                     lin_w, tok_w, out_w,
                                     linw_bf, tokw_bf, outw_bf, wn_bf, wnt_bf);
    k_pl2tok<<<dim3(6, 64, 16), 256, 0, stream>>>(bufE, bufC);        // xd token
    // GEMM1 (0..3071) ∥ f2bf8(freq) (3072..15359); bufE (xd plane) dead
    k_gemm_split<<<15360, 256, 0, stream>>>(bufC, linw_bf, lin_b,
                                            bufA, bufB, freq, bufE);  // xs PLANE, z token, freq bf16
    k_gemm_mod<<<1536, 256, 0, stream>>>(bufE, tokw_bf, tok_b,
                                         bufC);                       // v plane (xd tok dead)
    k_spectral<<<6144, 256, 0, stream>>>(bufA, bufC, wn_bf, wnt_bf,
                                         cp, ap, bufE);               // xo plane (freq bf dead)
    k_lnfuse<<<2048, 256, 0, stream>>>(bufE, bufB, ln_g, ln_b, bufC); // y token (v dead)
    k_gemm_f32out<<<1536, 256, 0, stream>>>(bufC, outw_bf, out_b, out);
}

// Round 11
// 474.923 us; speedup vs baseline: 1.0127x; 1.0127x over previous
//
#include <hip/hip_runtime.h>
#include <hip/hip_bf16.h>
#include <math.h>

// ---------------------------------------------------------------------------
// WaveFormer on MI355X.  B=16, C=384, H=W=64, T=B*H*W=65536 tokens.
//   [conv3x3 dw ∥ prep] -> pl2tok -> [GEMM1(lin) ∥ f2bf(freq), 1:4 block
//   interleave] -> xs PLANE, z token, freq bf16 -> GEMM2(pure) -> v PLANE
//   spectral per (b,c) plane: Wn^T((Wn P Wn^T) .* mod(v)) Wn, mod inline (r7)
//   fused LN(xo plane) * silu(z) -> y token -> GEMM3(out) -> d_out fp32
// GEMMs: m97-style 128x128 tile, BK=32, double-buffered global_load_lds w=16,
// XOR-swizzled LDS, XCD-aware grid, __launch_bounds__(256,4) (r11: r9's
// (256,3) landed at 60 VGPR + 64 AGPR = 124 <= 128 -> 4 waves/SIMD fits;
// LDS 34.8KB x4 = 139KB <= 160KB).
// r11: split∥f2bf merge is now INTERLEAVED (bid%5==0 -> GEMM, else f2bf) --
// r10's block-range partition was purely additive (91 = 63+28us) because
// in-order dispatch ran all GEMM blocks before any f2bf block; 1:4 interleave
// keeps GEMM blocks resident while short f2bf blocks stream through freed
// slots.
// r8: spectral tiles XOR-swizzled (25.6M conflict cycles -> ~0).
// lnfuse v2: 32 tok/block, linearized output (r6).
// Workspace: 2 x 48MB ping-pong + ~1.2MB weights. d_out doubles as xs/z
// scratch until GEMM3.
// ---------------------------------------------------------------------------

typedef __attribute__((ext_vector_type(8))) short short8;   // 8 bf16
typedef __attribute__((ext_vector_type(4))) float floatx4;

#define PIF 3.14159265358979323846f

__device__ __forceinline__ short f2bf(float f) {
    union { float f; unsigned u; } v; v.f = f;
    unsigned r = v.u + 0x7fffu + ((v.u >> 16) & 1u);   // RNE
    return (short)(r >> 16);
}
__device__ __forceinline__ float bf2f(short s) {
    union { unsigned u; float f; } v;
    v.u = ((unsigned)(unsigned short)s) << 16;
    return v.f;
}
// erf(x) via Abramowitz-Stegun 7.1.26 (max abs err 1.5e-7), fast __expf
__device__ __forceinline__ float fast_erf(float x) {
    float ax = fabsf(x);
    float t = 1.0f / fmaf(0.3275911f, ax, 1.0f);
    float poly = t * fmaf(t, fmaf(t, fmaf(t, fmaf(t, 1.061405429f, -1.453152027f),
                                          1.421413741f), -0.284496736f), 0.254829592f);
    float er = 1.0f - poly * __expf(-ax * ax);
    return copysignf(er, x);
}

// async global->LDS, 16B per lane. lds ptr must be wave-uniform base.
__device__ __forceinline__ void gload16(const short* g, short* l) {
    __builtin_amdgcn_global_load_lds(
        (const __attribute__((address_space(1))) void*)g,
        (__attribute__((address_space(3))) void*)l, 16, 0, 0);
}

// [64][64] bf16 tile swizzle: flip 16B slot by row bits (2-way banks = free)
__device__ __forceinline__ int swi(int r, int c) {
    return (r << 6) + (c ^ ((((r) & 7) ^ ((r >> 3) & 7)) << 3));
}

// ---- conv3x3 dw (blocks 0..6143) ∥ prep: weight converts + DCT (6144..) ----
__global__ __launch_bounds__(256) void k_conv(const float* __restrict__ x,
                                              const float* __restrict__ w,
                                              const float* __restrict__ bias,
                                              short* __restrict__ out,
                                              const float* __restrict__ lin_w,
                                              const float* __restrict__ tok_w,
                                              const float* __restrict__ out_w,
                                              short* __restrict__ linw_bf,
                                              short* __restrict__ tokw_bf,
                                              short* __restrict__ outw_bf,
                                              short* __restrict__ wn,
                                              short* __restrict__ wnt) {
    __shared__ float sp[4096];
    int bid = blockIdx.x;
    if (bid >= 6144) {
        int b = bid - 6144;
        if (b < 576) {
            const float* src; short* dst; int base;
            if (b < 288)      { src = lin_w; dst = linw_bf; base = b; }
            else if (b < 432) { src = tok_w; dst = tokw_bf; base = b - 288; }
            else              { src = out_w; dst = outw_bf; base = b - 432; }
            int i = (base * 256 + threadIdx.x) * 4;
            float4 f = *(const float4*)(src + i);
            short4 o;
            o.x = f2bf(f.x); o.y = f2bf(f.y); o.z = f2bf(f.z); o.w = f2bf(f.w);
            *(short4*)(dst + i) = o;
        } else {
            int i = (b - 576) * 256 + threadIdx.x;   // 0..4095
            int n = i >> 6, h = i & 63;
            float v = cosf((float)n * ((float)h + 0.5f) * (PIF / 64.0f)) * sqrtf(2.0f / 64.0f);
            if (n == 0) v *= 0.70710678118654752f;
            short bb = f2bf(v);
            wn[n * 64 + h]  = bb;   // [n][h]
            wnt[h * 64 + n] = bb;   // [h][n]
        }
        return;
    }
    int bc = bid;                     // b*384 + c
    int c = bc % 384;
    int tid = threadIdx.x;
    const float* xp = x + (size_t)bc * 4096;
    for (int i = 0; i < 4; i++) {
        int e = i * 1024 + tid * 4;
        *(float4*)(sp + e) = *(const float4*)(xp + e);
    }
    float wt[9];
    #pragma unroll
    for (int j = 0; j < 9; j++) wt[j] = w[c * 9 + j];
    float bv = bias[c];
    __syncthreads();
    short* op = out + (size_t)bc * 4096;
    for (int i = 0; i < 16; i++) {
        int hw = i * 256 + tid;
        int h = hw >> 6, ww = hw & 63;
        float acc = bv;
        #pragma unroll
        for (int dh = 0; dh < 3; dh++) {
            int ih = h + dh - 1;
            if (ih < 0 || ih > 63) continue;
            #pragma unroll
            for (int dw = 0; dw < 3; dw++) {
                int iw = ww + dw - 1;
                if (iw < 0 || iw > 63) continue;
                acc += sp[ih * 64 + iw] * wt[dh * 3 + dw];
            }
        }
        op[hw] = f2bf(acc);
    }
}

// ------- plane [B][C][4096] -> token [T][384] (xd only), short8 both sides --
__global__ __launch_bounds__(256) void k_pl2tok(const short* __restrict__ src,
                                                short* __restrict__ dst) {
    __shared__ short tile[4096];       // [hw][c], swi-swizzled
    int ct = blockIdx.x, ht = blockIdx.y, b = blockIdx.z;
    int tid = threadIdx.x;
    const short* sp = src + ((size_t)b * 384 + ct * 64) * 4096 + ht * 64;
    #pragma unroll
    for (int i = 0; i < 2; i++) {
        int q = i * 256 + tid;
        int r = q >> 3, c8 = (q & 7) * 8;          // r=c-local, c8=hw-col chunk
        short8 v = *(const short8*)(sp + (size_t)r * 4096 + c8);
        #pragma unroll
        for (int j = 0; j < 8; j++) tile[swi(c8 + j, r)] = v[j];   // tile[hw][c]
    }
    __syncthreads();
    short* dp = dst + ((size_t)b * 4096 + ht * 64) * 384 + ct * 64;
    #pragma unroll
    for (int i = 0; i < 2; i++) {
        int q = i * 256 + tid;
        int r2 = q >> 3, c8 = (q & 7) * 8;         // r2=hw row, c8=c-col chunk
        short8 v = *(const short8*)(tile + swi(r2, c8));
        *(short8*)(dp + (size_t)r2 * 384 + c8) = v;
    }
}

// ---------------------------------------------------------------------------
// Shared GEMM core (bf16 A): D-tile 128x128, K=384, BK=32, 256 threads.
// XOR-swizzled tile: 16B slot q holds chunk (row=q>>2, koff=(q&3)^((q>>3)&3)).
// smem: ldsA [2][512 slots] at 0, ldsB same at +8192 shorts.
// ---------------------------------------------------------------------------
__device__ __forceinline__ void mm_core(const short* __restrict__ A,
                                        const short* __restrict__ Bw,
                                        int row_base, int col_base,
                                        short* smem, floatx4 (&acc)[4][4]) {
    const int K = 384;
    int tid = threadIdx.x;
    int wid = tid >> 6, lane = tid & 63;
    int quad = lane >> 4, l16 = lane & 15;
    int rowh = (wid >> 1) * 64, colh = (wid & 1) * 64;
    short* ldsA = smem;
    short* ldsB = smem + 8192;
    const short* ga = A + (size_t)row_base * K;
    const short* gb = Bw + (size_t)col_base * K;

    int q0 = tid, q1 = 256 + tid;
    int r0 = q0 >> 2, o0 = ((q0 & 3) ^ ((q0 >> 3) & 3)) * 8;
    int r1 = q1 >> 2, o1 = ((q1 & 3) ^ ((q1 >> 3) & 3)) * 8;
    short* la0 = ldsA + (wid * 64) * 8;          // wave-uniform dests
    short* la1 = ldsA + (256 + wid * 64) * 8;
    short* lb0 = ldsB + (wid * 64) * 8;
    short* lb1 = ldsB + (256 + wid * 64) * 8;

    auto stage = [&](int ks, int buf) {
        int k0 = ks * 32;
        gload16(ga + (size_t)r0 * K + k0 + o0, la0 + buf * 4096);
        gload16(ga + (size_t)r1 * K + k0 + o1, la1 + buf * 4096);
        gload16(gb + (size_t)r0 * K + k0 + o0, lb0 + buf * 4096);
        gload16(gb + (size_t)r1 * K + k0 + o1, lb1 + buf * 4096);
    };

    int ksw = (quad ^ ((l16 >> 1) & 3)) * 8;     // per-lane swizzled k-slot

    stage(0, 0);
    __syncthreads();
    #pragma unroll 2
    for (int ks = 0; ks < 12; ++ks) {
        int cur = ks & 1;
        if (ks < 11) stage(ks + 1, cur ^ 1);
        short8 af[4], bfr[4];
        #pragma unroll
        for (int s = 0; s < 4; s++) {
            af[s]  = *(const short8*)(ldsA + cur * 4096 + (rowh + s * 16 + l16) * 32 + ksw);
            bfr[s] = *(const short8*)(ldsB + cur * 4096 + (colh + s * 16 + l16) * 32 + ksw);
        }
        #pragma unroll
        for (int i = 0; i < 4; i++)
            #pragma unroll
            for (int j = 0; j < 4; j++)
                acc[i][j] = __builtin_amdgcn_mfma_f32_16x16x32_bf16(af[i], bfr[j], acc[i][j], 0, 0, 0);
        __syncthreads();
    }
}

// -------- GEMM1 ∥ f2bf8(freq), 1:4 INTERLEAVED over 15360 blocks ----------
// bid%5==0: GEMM block sbid=bid/5 (0..3071); else f2bf block
// fb=(bid/5)*4+(bid%5-1) (0..12287).
__global__ __launch_bounds__(256, 4) void k_gemm_split(const short* __restrict__ A,
                                                       const short* __restrict__ Bw,
                                                       const float* __restrict__ bias,
                                                       short* __restrict__ xs_pl,
                                                       short* __restrict__ z_tok,
                                                       const float* __restrict__ freqf,
                                                       short* __restrict__ freqbf) {
    __shared__ __align__(16) short smem[17408];  // staging 16384 | tile 128*136
    int bid = blockIdx.x;
    int sbid = bid / 5;
    int rem = bid - sbid * 5;
    if (rem) {
        int fb = sbid * 4 + rem - 1;
        int i = (fb * 256 + threadIdx.x) * 8;
        float4 a = *(const float4*)(freqf + i);
        float4 b = *(const float4*)(freqf + i + 4);
        short8 o;
        o[0] = f2bf(a.x); o[1] = f2bf(a.y); o[2] = f2bf(a.z); o[3] = f2bf(a.w);
        o[4] = f2bf(b.x); o[5] = f2bf(b.y); o[6] = f2bf(b.z); o[7] = f2bf(b.w);
        *(short8*)(freqbf + i) = o;
        return;
    }
    int xcd = sbid & 7, local = sbid >> 3;       // 384 GEMM blocks per XCD
    int bx = local % 6;
    int by = xcd * 64 + local / 6;
    int row_base = by * 128, col_base = bx * 128;
    int tid = threadIdx.x;
    int wid = tid >> 6, lane = tid & 63, quad = lane >> 4, l16 = lane & 15;
    int rowh = (wid >> 1) * 64, colh = (wid & 1) * 64;

    floatx4 zero = {0.f, 0.f, 0.f, 0.f};
    floatx4 acc[4][4];
    #pragma unroll
    for (int i = 0; i < 4; i++)
        #pragma unroll
        for (int j = 0; j < 4; j++) acc[i][j] = zero;

    mm_core(A, Bw, row_base, col_base, smem, acc);

    if (bx < 3) {
        // xs half: transpose through smem (staging dead), store plane layout
        #pragma unroll
        for (int i = 0; i < 4; i++)
            #pragma unroll
            for (int j = 0; j < 4; j++) {
                int cl = colh + j * 16 + l16;            // channel-local 0..127
                float bs = bias[col_base + cl];
                #pragma unroll
                for (int r = 0; r < 4; r++) {
                    int rl = rowh + i * 16 + quad * 4 + r;   // token-local 0..127
                    smem[cl * 136 + rl] = f2bf(acc[i][j][r] + bs);
                }
            }
        __syncthreads();
        int t0 = row_base;                 // 128 tokens, same b
        int b = t0 >> 12, hw0 = t0 & 4095;
        for (int it = 0; it < 8; it++) {
            int q = it * 256 + tid;
            int cl = q >> 4, t8 = (q & 15) * 8;
            short8 vv = *(const short8*)(smem + cl * 136 + t8);
            int c = col_base + cl;
            *(short8*)(xs_pl + ((size_t)b * 384 + c) * 4096 + hw0 + t8) = vv;
        }
    } else {
        // z half: token layout direct
        #pragma unroll
        for (int i = 0; i < 4; i++)
            #pragma unroll
            for (int j = 0; j < 4; j++) {
                int col = col_base + colh + j * 16 + l16;
                float bs = bias[col];
                int cc = col - 384;
                #pragma unroll
                for (int r = 0; r < 4; r++) {
                    int row = row_base + rowh + i * 16 + quad * 4 + r;
                    z_tok[(size_t)row * 384 + cc] = f2bf(acc[i][j][r] + bs);
                }
            }
    }
}

// -------- GEMM2 (pure): v = freq @ tokw^T + b, stored PLANE layout ---------
__global__ __launch_bounds__(256, 4) void k_gemm_mod(const short* __restrict__ A,
                                                     const short* __restrict__ Bw,
                                                     const float* __restrict__ bias,
                                                     short* __restrict__ Dpl) {
    __shared__ __align__(16) short smem[17408];
    int bid = blockIdx.x;
    int xcd = bid & 7, local = bid >> 3;         // 192 blocks per XCD
    int bx = local % 3;
    int by = xcd * 64 + local / 3;
    int row_base = by * 128, col_base = bx * 128;
    int tid = threadIdx.x;
    int wid = tid >> 6, lane = tid & 63, quad = lane >> 4, l16 = lane & 15;
    int rowh = (wid >> 1) * 64, colh = (wid & 1) * 64;

    floatx4 zero = {0.f, 0.f, 0.f, 0.f};
    floatx4 acc[4][4];
    #pragma unroll
    for (int i = 0; i < 4; i++)
        #pragma unroll
        for (int j = 0; j < 4; j++) acc[i][j] = zero;

    mm_core(A, Bw, row_base, col_base, smem, acc);

    // transpose through smem (staging dead), store v plane layout
    #pragma unroll
    for (int i = 0; i < 4; i++) {
        #pragma unroll
        for (int j = 0; j < 4; j++) {
            int cl = colh + j * 16 + l16;
            float bs = bias[col_base + cl];
            #pragma unroll
            for (int r = 0; r < 4; r++) {
                int rl = rowh + i * 16 + quad * 4 + r;
                smem[cl * 136 + rl] = f2bf(acc[i][j][r] + bs);
            }
        }
    }
    __syncthreads();
    int t0 = row_base;
    int b = t0 >> 12, hw0 = t0 & 4095;
    for (int it = 0; it < 8; it++) {
        int q = it * 256 + tid;
        int cl = q >> 4, t8 = (q & 15) * 8;
        short8 vv = *(const short8*)(smem + cl * 136 + t8);
        int c = col_base + cl;
        *(short8*)(Dpl + ((size_t)b * 384 + c) * 4096 + hw0 + t8) = vv;
    }
}

// ---------------- spectral: per (b,c) plane, 4 chained 64x64x64 MFMA GEMMs ----
// xo = Wn^T ((Wn P Wn^T) .* mod(v)) Wn, mod computed inline from v plane.
// All LDS tiles XOR-swizzled via swi(); Wn/Wt/M use pre-swizzled global slot.
__global__ __launch_bounds__(256) void k_spectral(const short* __restrict__ xs,   // [B][C][4096] [h][w]
                                                  const short* __restrict__ vpl,  // [B][C][4096] [n][m] pre-act
                                                  const short* __restrict__ wn,   // [n][h]
                                                  const short* __restrict__ wnt,  // [h][n]
                                                  const float* __restrict__ cp,
                                                  const float* __restrict__ ap,
                                                  short* __restrict__ xo) {       // [B][C][4096]
    __shared__ short sWn[4096], sWt[4096], sP[4096], sM[4096], sT[4096];
    int bc = blockIdx.x;
    int tid = threadIdx.x;
    int wid = tid >> 6, lane = tid & 63, quad = lane >> 4, l16 = lane & 15;
    const short* xp = xs + (size_t)bc * 4096;
    const short* mp = vpl + (size_t)bc * 4096;
    floatx4 zero = {0.f, 0.f, 0.f, 0.f};

    for (int i = 0; i < 2; i++) {
        int e = i * 2048 + tid * 8;
        int row = e >> 6, slot = (e >> 3) & 7;
        // pre-swizzled global slot; LDS store linear -> content[row][c^S(row)]
        int gx = (row << 6) + (((slot ^ (row & 7) ^ ((row >> 3) & 7)) & 7) << 3);
        *(short8*)(sWn + e) = *(const short8*)(wn + gx);
        *(short8*)(sWt + e) = *(const short8*)(wnt + gx);
        *(short8*)(sM + e)  = *(const short8*)(mp + gx);
        short8 pv = *(const short8*)(xp + e);       // linear coalesced read
        int h = row, w0 = e & 63;
        #pragma unroll
        for (int j = 0; j < 8; j++) sP[swi(w0 + j, h)] = pv[j];   // sP = P^T [w][h]
    }
    __syncthreads();

    int mrow = wid * 16;   // this wave's 16 output rows at every stage
    floatx4 acc[4];

    // S1: T1[n][w] = sum_h Wn[n][h] P[h][w]
    #pragma unroll
    for (int j = 0; j < 4; j++) acc[j] = zero;
    #pragma unroll
    for (int ks = 0; ks < 2; ks++) {
        int k0 = ks * 32 + quad * 8;
        short8 a = *(const short8*)(sWn + swi(mrow + l16, k0));
        #pragma unroll
        for (int j = 0; j < 4; j++) {
            short8 b = *(const short8*)(sP + swi(j * 16 + l16, k0));
            acc[j] = __builtin_amdgcn_mfma_f32_16x16x32_bf16(a, b, acc[j], 0, 0, 0);
        }
    }
    #pragma unroll
    for (int j = 0; j < 4; j++)
        #pragma unroll
        for (int r = 0; r < 4; r++)
            sT[swi(mrow + quad * 4 + r, j * 16 + l16)] = f2bf(acc[j][r]);  // sT = T1 [n][w]
    __syncthreads();

    // S2: T2[n][m] = sum_w T1[n][w] Wn[m][w]
    #pragma unroll
    for (int j = 0; j < 4; j++) acc[j] = zero;
    #pragma unroll
    for (int ks = 0; ks < 2; ks++) {
        int k0 = ks * 32 + quad * 8;
        short8 a = *(const short8*)(sT + swi(mrow + l16, k0));
        #pragma unroll
        for (int j = 0; j < 4; j++) {
            short8 b = *(const short8*)(sWn + swi(j * 16 + l16, k0));
            acc[j] = __builtin_amdgcn_mfma_f32_16x16x32_bf16(a, b, acc[j], 0, 0, 0);
        }
    }
    __syncthreads();
    // epilogue: compute mod from v inline, multiply, store transposed [m][n]
    {
        float cv = cp[0], av = ap[0];
        float inv_c = 1.0f / (cv + 1e-8f);
        float gfac = 1.0f + 0.5f * av;
        #pragma unroll
        for (int j = 0; j < 4; j++)
            #pragma unroll
            for (int r = 0; r < 4; r++) {
                int n = mrow + quad * 4 + r, m = j * 16 + l16;
                float v = bf2f(sM[swi(n, m)]);
                float t = 0.5f * v * (1.0f + fast_erf(v * 0.70710678118654752f));
                float sn, cs;
                __sincosf(cv * t, &sn, &cs);
                float fac = cs + sn * inv_c * gfac;
                float wnf = (float)n * (PIF / 64.0f);
                float wmf = (float)m * (PIF / 64.0f);
                float mod = fac * __expf(-(wnf * wnf + wmf * wmf) * t);
                sP[swi(m, n)] = f2bf(acc[j][r] * mod);
            }
    }
    __syncthreads();

    // S3: T3[h][m] = sum_n WnT[h][n] T2'[n][m]
    #pragma unroll
    for (int j = 0; j < 4; j++) acc[j] = zero;
    #pragma unroll
    for (int ks = 0; ks < 2; ks++) {
        int k0 = ks * 32 + quad * 8;
        short8 a = *(const short8*)(sWt + swi(mrow + l16, k0));
        #pragma unroll
        for (int j = 0; j < 4; j++) {
            short8 b = *(const short8*)(sP + swi(j * 16 + l16, k0));
            acc[j] = __builtin_amdgcn_mfma_f32_16x16x32_bf16(a, b, acc[j], 0, 0, 0);
        }
    }
    __syncthreads();
    #pragma unroll
    for (int j = 0; j < 4; j++)
        #pragma unroll
        for (int r = 0; r < 4; r++)
            sT[swi(mrow + quad * 4 + r, j * 16 + l16)] = f2bf(acc[j][r]);  // sT = T3 [h][m]
    __syncthreads();

    // S4: XO[h][w] = sum_m T3[h][m] Wn[m][w]
    #pragma unroll
    for (int j = 0; j < 4; j++) acc[j] = zero;
    #pragma unroll
    for (int ks = 0; ks < 2; ks++) {
        int k0 = ks * 32 + quad * 8;
        short8 a = *(const short8*)(sT + swi(mrow + l16, k0));
        #pragma unroll
        for (int j = 0; j < 4; j++) {
            short8 b = *(const short8*)(sWt + swi(j * 16 + l16, k0));
            acc[j] = __builtin_amdgcn_mfma_f32_16x16x32_bf16(a, b, acc[j], 0, 0, 0);
        }
    }
    short* op = xo + (size_t)bc * 4096;
    #pragma unroll
    for (int j = 0; j < 4; j++)
        #pragma unroll
        for (int r = 0; r < 4; r++) {
            int h = mrow + quad * 4 + r, w = j * 16 + l16;
            op[h * 64 + w] = f2bf(acc[j][r]);
        }
}

// ------- fused v2: xo PLANE -> LN over C -> * silu(z) -> y token ----------
// 32 tokens/block (one b, contiguous hw), grid 2048. LDS ~25 KB -> 6 blk/CU.
// Output loop linear in m: y/z offset = t0*384 + 8*m (fully coalesced).
__global__ __launch_bounds__(256) void k_lnfuse(const short* __restrict__ xo_pl, // [B][C][4096]
                                                const short* __restrict__ z,     // [T][384]
                                                const float* __restrict__ g,
                                                const float* __restrict__ bb,
                                                short* __restrict__ y) {         // [T][384]
    __shared__ short tile[32 * 392];     // [tok][c], stride 392 (16B-aligned rows)
    __shared__ float smu[32], srstd[32];
    int tid = threadIdx.x;
    int t0 = blockIdx.x * 32;
    int b = t0 >> 12, hw0 = t0 & 4095;

    // fill: 1536 chunks (384 c x 4 t8-chunks); tch fastest -> 64B global segs
    for (int it = 0; it < 6; it++) {
        int m = it * 256 + tid;
        int c = m >> 2, t8 = (m & 3) * 8;
        short8 v = *(const short8*)(xo_pl + ((size_t)b * 384 + c) * 4096 + hw0 + t8);
        #pragma unroll
        for (int j = 0; j < 8; j++) tile[(t8 + j) * 392 + c] = v[j];
    }
    __syncthreads();

    // LN stats: 8 threads per token (t = tid>>3), 48 channels each
    {
        int t = tid >> 3, g8 = tid & 7;
        const short* trow = tile + t * 392 + g8 * 48;
        float s = 0.f, sq = 0.f;
        #pragma unroll
        for (int i = 0; i < 6; i++) {
            short8 xv = *(const short8*)(trow + i * 8);
            #pragma unroll
            for (int j = 0; j < 8; j++) {
                float f = bf2f(xv[j]);
                s += f; sq += f * f;
            }
        }
        s  += __shfl_xor(s, 1, 64);  s  += __shfl_xor(s, 2, 64);  s  += __shfl_xor(s, 4, 64);
        sq += __shfl_xor(sq, 1, 64); sq += __shfl_xor(sq, 2, 64); sq += __shfl_xor(sq, 4, 64);
        if (g8 == 0) {
            float mu = s * (1.0f / 384.0f);
            float var = sq * (1.0f / 384.0f) - mu * mu;
            smu[t] = mu;
            srstd[t] = rsqrtf(var + 1e-5f);
        }
    }
    __syncthreads();

    // output: linear chunks, tok = m/48, ch = (m%48)*8; y/z addr = t0*384+8m
    for (int it = 0; it < 6; it++) {
        int m = it * 256 + tid;
        int tok = m / 48, ch = (m - tok * 48) * 8;
        float mu = smu[tok], rstd = srstd[tok];
        short8 xv = *(const short8*)(tile + tok * 392 + ch);
        const size_t goff = (size_t)(t0 + tok) * 384 + ch;
        short8 zv = *(const short8*)(z + goff);
        float4 g0 = *(const float4*)(g + ch);
        float4 g1 = *(const float4*)(g + ch + 4);
        float4 b0 = *(const float4*)(bb + ch);
        float4 b1 = *(const float4*)(bb + ch + 4);
        float gv[8] = {g0.x, g0.y, g0.z, g0.w, g1.x, g1.y, g1.z, g1.w};
        float bv[8] = {b0.x, b0.y, b0.z, b0.w, b1.x, b1.y, b1.z, b1.w};
        short8 ov;
        #pragma unroll
        for (int j = 0; j < 8; j++) {
            float zz = bf2f(zv[j]);
            float sil = zz / (1.f + __expf(-zz));
            float o = (bf2f(xv[j]) - mu) * rstd * gv[j] + bv[j];
            ov[j] = f2bf(o * sil);
        }
        *(short8*)(y + goff) = ov;
    }
}

// -------- GEMM3: out[M,384] = Y[M,384] * out_w^T + bias, fp32 store ---------
__global__ __launch_bounds__(256, 4) void k_gemm_f32out(const short* __restrict__ A,
                                                        const short* __restrict__ Bw,
                                                        const float* __restrict__ bias,
                                                        float* __restrict__ D) {
    __shared__ __align__(16) short smem[17408];
    const int N = 384;
    int bid = blockIdx.x;
    int xcd = bid & 7, local = bid >> 3;
    int bx = local % 3;
    int by = xcd * 64 + local / 3;
    int row_base = by * 128, col_base = bx * 128;
    int tid = threadIdx.x;
    int wid = tid >> 6, lane = tid & 63, quad = lane >> 4, l16 = lane & 15;
    int rowh = (wid >> 1) * 64, colh = (wid & 1) * 64;

    floatx4 zero = {0.f, 0.f, 0.f, 0.f};
    floatx4 acc[4][4];
    #pragma unroll
    for (int i = 0; i < 4; i++)
        #pragma unroll
        for (int j = 0; j < 4; j++) acc[i][j] = zero;

    mm_core(A, Bw, row_base, col_base, smem, acc);

    #pragma unroll
    for (int i = 0; i < 4; i++) {
        #pragma unroll
        for (int j = 0; j < 4; j++) {
            int col = col_base + colh + j * 16 + l16;
            float bs = bias[col];
            #pragma unroll
            for (int r = 0; r < 4; r++) {
                int row = row_base + rowh + i * 16 + quad * 4 + r;
                D[(size_t)row * N + col] = acc[i][j][r] + bs;
            }
        }
    }
}

// ---------------------------------------------------------------------------
extern "C" void kernel_launch(void* const* d_in, const int* in_sizes, int n_in,
                              void* d_out, int out_size, void* d_ws, size_t ws_size,
                              hipStream_t stream) {
    const float* x     = (const float*)d_in[0];
    const float* freq  = (const float*)d_in[1];
    const float* dw_w  = (const float*)d_in[2];
    const float* dw_b  = (const float*)d_in[3];
    const float* lin_w = (const float*)d_in[4];
    const float* lin_b = (const float*)d_in[5];
    const float* tok_w = (const float*)d_in[6];
    const float* tok_b = (const float*)d_in[7];
    const float* ln_g  = (const float*)d_in[8];
    const float* ln_b  = (const float*)d_in[9];
    const float* out_w = (const float*)d_in[10];
    const float* out_b = (const float*)d_in[11];
    const float* cp    = (const float*)d_in[12];
    const float* ap    = (const float*)d_in[13];
    float* out = (float*)d_out;
    (void)in_sizes; (void)n_in; (void)ws_size;

    // d_out (96MiB fp32) doubles as two 48MiB bf16 scratch tensors until GEMM3.
    const size_t TC = (size_t)65536 * 384;   // 25165824
    short* bufA = (short*)d_out;             // xs plane (dead after spectral)
    short* bufB = (short*)d_out + TC;        // z token (alive until lnfuse)

    char* ws = (char*)d_ws;
    size_t off = 0;
    auto alloc = [&](size_t bytes) {
        char* p = ws + off; off += (bytes + 255) & ~(size_t)255; return p;
    };
    short* wn_bf   = (short*)alloc(4096 * 2);
    short* wnt_bf  = (short*)alloc(4096 * 2);
    short* linw_bf = (short*)alloc((size_t)294912 * 2);
    short* tokw_bf = (short*)alloc((size_t)147456 * 2);
    short* outw_bf = (short*)alloc((size_t)147456 * 2);
    short* bufC    = (short*)alloc(TC * 2);  // xd token -> v plane -> y token
    short* bufE    = (short*)alloc(TC * 2);  // xd plane -> freq bf16 -> xo plane
    // total ws: ~98.3 MB

    // conv (0..6143) ∥ prep (6144..6735)
    k_conv<<<6736, 256, 0, stream>>>(x, dw_w, dw_b, bufE,
                                     lin_w, tok_w, out_w,
                                     linw_bf, tokw_bf, outw_bf, wn_bf, wnt_bf);
    k_pl2tok<<<dim3(6, 64, 16), 256, 0, stream>>>(bufE, bufC);        // xd token
    // GEMM1 ∥ f2bf8(freq), 1:4 interleaved; bufE (xd plane) dead
    k_gemm_split<<<15360, 256, 0, stream>>>(bufC, linw_bf, lin_b,
                                            bufA, bufB, freq, bufE);  // xs PLANE, z token, freq bf16
    k_gemm_mod<<<1536, 256, 0, stream>>>(bufE, tokw_bf, tok_b,
                                         bufC);                       // v plane (xd tok dead)
    k_spectral<<<6144, 256, 0, stream>>>(bufA, bufC, wn_bf, wnt_bf,
                                         cp, ap, bufE);               // xo plane (freq bf dead)
    k_lnfuse<<<2048, 256, 0, stream>>>(bufE, bufB, ln_g, ln_b, bufC); // y token (v dead)
    k_gemm_f32out<<<1536, 256, 0, stream>>>(bufC, outw_bf, out_b, out);
}